// Round 5
// baseline (327.041 us; speedup 1.0000x reference)
//
#include <hip/hip_runtime.h>
#include <math.h>

#define NN 50000
#define NE 800000
#define DD 128
#define NBUCK 196        // ceil(NN/256) buckets of 256 nodes
#define EPB 2048         // edges per hist/partition block
#define PB 391           // ceil(NE/EPB)
#define CONVB 6250       // NN*DD/4/256
#define NTILE 782        // ceil(NN/64) node tiles per feature chunk
#define NTILES4 (NTILE * 4)

typedef unsigned short u16;
typedef unsigned long long u64t;
typedef short s8v __attribute__((ext_vector_type(8)));    // 8 bf16 (4 VGPRs)
typedef float f16v __attribute__((ext_vector_type(16)));  // 16 fp32 acc

__device__ __forceinline__ u16 f2bf(float f) {  // RNE fp32->bf16
    unsigned u = __float_as_uint(f);
    return (u16)((u + 0x7FFFu + ((u >> 16) & 1u)) >> 16);
}
__device__ __forceinline__ float bflo(unsigned u) { return __uint_as_float(u << 16); }
__device__ __forceinline__ float bfhi(unsigned u) { return __uint_as_float(u & 0xFFFF0000u); }

// ---- zero bcnt + claim + queue counters (graph-capture-safe) ----
__global__ __launch_bounds__(256) void zero_kernel(int* __restrict__ p, int n) {
    int i = threadIdx.x + blockIdx.x * 256;
    if (i < n) p[i] = 0;
}

// ---- fused prep: x->bf16 conv (row-major + chunk-major) | 3x weight pack | hist ----
// pack order: out[((c*4+n)*64+l)*8+j] = Wcat[col=n*32+(l&31)][k=c*16+(l>>5)*8+j]
__device__ __forceinline__ void pack_one(const float* __restrict__ Wl,
                                         const float* __restrict__ Wr,
                                         bool two, int o, u16* __restrict__ out) {
    int j = o & 7;
    int l = (o >> 3) & 63;
    int cn = o >> 9;
    int n = cn & 3;
    int c = cn >> 2;
    int colj = n * 32 + (l & 31);
    int k = c * 16 + (l >> 5) * 8 + j;
    float v;
    if (two) v = (k < DD) ? Wl[colj * DD + k] : Wr[colj * DD + (k - DD)];
    else     v = Wl[colj * DD + k];
    out[o] = f2bf(v);
}

__global__ __launch_bounds__(256) void prep_kernel(
        const float4* __restrict__ x4, ushort4* __restrict__ hb0,
        ushort4* __restrict__ hbT,
        const float* __restrict__ Wl, const float* __restrict__ Wr,
        const float* __restrict__ W,
        u16* __restrict__ Bpk0, u16* __restrict__ Bpk1, u16* __restrict__ Bpkf,
        const int* __restrict__ ei, int* __restrict__ bcnt) {
    int bid = blockIdx.x;
    int tid = threadIdx.x;
    if (bid < CONVB) {
        int i = bid * 256 + tid;
        float4 v = x4[i];
        ushort4 o;
        o.x = f2bf(v.x); o.y = f2bf(v.y); o.z = f2bf(v.z); o.w = f2bf(v.w);
        hb0[i] = o;
        // chunk-major mirror: node = i>>5, pos = i&31, chunk = pos>>3, sub = pos&7
        int node = i >> 5, pos = i & 31;
        hbT[((size_t)((pos >> 3) * NN + node) << 3) + (pos & 7)] = o;
    } else if (bid < CONVB + 128) {
        pack_one(Wl, Wr, true, (bid - CONVB) * 256 + tid, Bpk0);
    } else if (bid < CONVB + 256) {
        pack_one(Wl + DD * DD, Wr + DD * DD, true, (bid - CONVB - 128) * 256 + tid, Bpk1);
    } else if (bid < CONVB + 320) {
        pack_one(W, W, false, (bid - CONVB - 256) * 256 + tid, Bpkf);
    } else {
        // coarse bucket histogram (bcnt zeroed by zero_kernel)
        __shared__ int h[NBUCK];
        for (int i = tid; i < NBUCK; i += 256) h[i] = 0;
        __syncthreads();
        int e0 = (bid - (CONVB + 320)) * EPB;
#pragma unroll
        for (int i = 0; i < 8; i++) {
            int e = e0 + i * 256 + tid;
            if (e < NE) atomicAdd(&h[ei[NE + e] >> 8], 1);
        }
        __syncthreads();
        for (int i = tid; i < NBUCK; i += 256)
            if (h[i]) atomicAdd(&bcnt[i], h[i]);
    }
}

// ---- partition edges into bucket-contiguous packed array ----
__global__ __launch_bounds__(256) void bucket_partition(const int* __restrict__ ei,
                                                        const int* __restrict__ bcnt,
                                                        int* __restrict__ claim,
                                                        unsigned* __restrict__ packed,
                                                        int* __restrict__ rowptr) {
    __shared__ int sc[256];
    __shared__ int bb[NBUCK];
    __shared__ int h[NBUCK];
    __shared__ int base[NBUCK];
    int t = threadIdx.x;
    int v = (t < NBUCK) ? bcnt[t] : 0;
    sc[t] = v;
    __syncthreads();
    for (int o = 1; o < 256; o <<= 1) {
        int u = (t >= o) ? sc[t - o] : 0;
        __syncthreads();
        sc[t] += u;
        __syncthreads();
    }
    if (t < NBUCK) bb[t] = sc[t] - v;
    if (t == 0 && blockIdx.x == 0) rowptr[NN] = NE;
    for (int i = t; i < NBUCK; i += 256) h[i] = 0;
    __syncthreads();
    int e0 = blockIdx.x * EPB;
    int dsts[8], srcs[8];
#pragma unroll
    for (int i = 0; i < 8; i++) {
        int e = e0 + i * 256 + t;
        if (e < NE) {
            dsts[i] = ei[NE + e];
            srcs[i] = ei[e];
            atomicAdd(&h[dsts[i] >> 8], 1);
        } else dsts[i] = -1;
    }
    __syncthreads();
    for (int i = t; i < NBUCK; i += 256) {
        int c = h[i];
        base[i] = c ? bb[i] + atomicAdd(&claim[i], c) : 0;
    }
    __syncthreads();
    for (int i = t; i < NBUCK; i += 256) h[i] = 0;  // reuse as local cursor
    __syncthreads();
#pragma unroll
    for (int i = 0; i < 8; i++) {
        if (dsts[i] >= 0) {
            int bk = dsts[i] >> 8;
            int r = atomicAdd(&h[bk], 1);
            packed[base[bk] + r] = (unsigned)srcs[i] | ((unsigned)(dsts[i] & 255) << 16);
        }
    }
}

// ---- per-bucket counting sort -> rowptr + col ----
__global__ __launch_bounds__(256) void bucket_csr(const unsigned* __restrict__ packed,
                                                  const int* __restrict__ bcnt,
                                                  int* __restrict__ rowptr,
                                                  int* __restrict__ col) {
    __shared__ int sc[256];
    __shared__ int deg[256];
    __shared__ int off[256];
    int t = threadIdx.x;
    int v0 = (t < NBUCK) ? bcnt[t] : 0;
    sc[t] = v0;
    __syncthreads();
    for (int o = 1; o < 256; o <<= 1) {
        int u = (t >= o) ? sc[t - o] : 0;
        __syncthreads();
        sc[t] += u;
        __syncthreads();
    }
    int bk = blockIdx.x;
    int cnt = bcnt[bk];
    int base = sc[bk] - cnt;  // exclusive scan value for this bucket
    deg[t] = 0;
    __syncthreads();
    for (int i = t; i < cnt; i += 256) atomicAdd(&deg[packed[base + i] >> 16], 1);
    __syncthreads();
    int v = deg[t];
    off[t] = v;
    __syncthreads();
    for (int o = 1; o < 256; o <<= 1) {
        int u = (t >= o) ? off[t - o] : 0;
        __syncthreads();
        off[t] += u;
        __syncthreads();
    }
    int ex = off[t] - v;
    int node = (bk << 8) + t;
    if (node < NN) rowptr[node] = base + ex;
    deg[t] = ex;  // reuse as cursor
    __syncthreads();
    for (int i = t; i < cnt; i += 256) {
        unsigned p = packed[base + i];
        int dl = p >> 16;
        int r = atomicAdd(&deg[dl], 1);
        col[base + r] = (int)(p & 0xFFFFu);
    }
}

// ---- chunked segmented max with TEMPORAL chunk serialization (work-queue) ----
// Tiles ordered chunk-major: t/NTILE = chunk, t%NTILE = 64-node tile. A global
// atomic ticket queue keeps co-resident blocks inside a ~256-tile window (~1MB of
// chunk data live at once), so every XCD's L2 caches the whole active 3.2MB chunk
// (replicated) regardless of block->XCD mapping. 4 lanes/node x 16B = one 64B row
// read per edge, coalesced to a single transaction.
__device__ __forceinline__ void vmax8(float* m, uint4 v) {
    m[0] = fmaxf(m[0], bflo(v.x)); m[1] = fmaxf(m[1], bfhi(v.x));
    m[2] = fmaxf(m[2], bflo(v.y)); m[3] = fmaxf(m[3], bfhi(v.y));
    m[4] = fmaxf(m[4], bflo(v.z)); m[5] = fmaxf(m[5], bfhi(v.z));
    m[6] = fmaxf(m[6], bflo(v.w)); m[7] = fmaxf(m[7], bfhi(v.w));
}

__global__ __launch_bounds__(256) void agg_chunked_q(const uint4* __restrict__ hbT4,
                                                     const int* __restrict__ rowptr,
                                                     const int* __restrict__ col,
                                                     uint4* __restrict__ aggb4,
                                                     int* __restrict__ qctr) {
    __shared__ int s_t;
    int tid = threadIdx.x;
    for (;;) {
        __syncthreads();
        if (tid == 0) s_t = atomicAdd(qctr, 1);
        __syncthreads();
        int t = s_t;
        if (t >= NTILES4) return;
        int chunk = t / NTILE;
        int ntile = t - chunk * NTILE;
        int node = ntile * 64 + (tid >> 2);
        int q = tid & 3;
        bool valid = (node < NN);
        int s0 = 0, s1 = 0;
        if (valid) { s0 = rowptr[node]; s1 = rowptr[node + 1]; }
        const uint4* src4 = hbT4 + ((size_t)chunk * NN) * 4 + q;
        uint4 o = make_uint4(0u, 0u, 0u, 0u);
        if (s0 < s1) {
            float m0[8], m1[8];
#pragma unroll
            for (int k = 0; k < 8; k++) { m0[k] = m1[k] = -INFINITY; }
            int i = s0;
            for (; i + 8 <= s1; i += 8) {
                int c0 = col[i],     c1 = col[i + 1], c2 = col[i + 2], c3 = col[i + 3];
                int c4 = col[i + 4], c5 = col[i + 5], c6 = col[i + 6], c7 = col[i + 7];
                uint4 v0 = src4[(size_t)c0 * 4];
                uint4 v1 = src4[(size_t)c1 * 4];
                uint4 v2 = src4[(size_t)c2 * 4];
                uint4 v3 = src4[(size_t)c3 * 4];
                uint4 v4 = src4[(size_t)c4 * 4];
                uint4 v5 = src4[(size_t)c5 * 4];
                uint4 v6 = src4[(size_t)c6 * 4];
                uint4 v7 = src4[(size_t)c7 * 4];
                vmax8(m0, v0); vmax8(m1, v1); vmax8(m0, v2); vmax8(m1, v3);
                vmax8(m0, v4); vmax8(m1, v5); vmax8(m0, v6); vmax8(m1, v7);
            }
            for (; i + 2 <= s1; i += 2) {
                int c0 = col[i], c1 = col[i + 1];
                uint4 v0 = src4[(size_t)c0 * 4];
                uint4 v1 = src4[(size_t)c1 * 4];
                vmax8(m0, v0); vmax8(m1, v1);
            }
            if (i < s1) {
                uint4 v = src4[(size_t)col[i] * 4];
                vmax8(m0, v);
            }
#pragma unroll
            for (int k = 0; k < 8; k++) m0[k] = fmaxf(m0[k], m1[k]);
            // values exact bf16 -> pack by truncation
            o.x = (__float_as_uint(m0[0]) >> 16) | (__float_as_uint(m0[1]) & 0xFFFF0000u);
            o.y = (__float_as_uint(m0[2]) >> 16) | (__float_as_uint(m0[3]) & 0xFFFF0000u);
            o.z = (__float_as_uint(m0[4]) >> 16) | (__float_as_uint(m0[5]) & 0xFFFF0000u);
            o.w = (__float_as_uint(m0[6]) >> 16) | (__float_as_uint(m0[7]) & 0xFFFF0000u);
        }
        if (valid) aggb4[(size_t)node * 16 + chunk * 4 + q] = o;
    }
}

// ---------------- MFMA GEMM layer 0: LDS-staged epilogue, dual-layout output ----
// out[row][col] = relu(bias[col] + sum_k A[row][k]*Wcat[col][k]); A=[aggb|hb0], K=256.
// Output written row-major (hb1) AND chunk-major (hbT, layer-1 agg input), both coalesced.
__global__ __launch_bounds__(256) void mfma_gemm0(const u16* __restrict__ srcA,
                                                  const u16* __restrict__ srcB,
                                                  const u16* __restrict__ Bpk,
                                                  const float* __restrict__ bias,
                                                  u16* __restrict__ outh,
                                                  u16* __restrict__ outT) {
    __shared__ u16 As[128 * 128];  // 32 KB, XOR-swizzled rows
    char* Ab = (char*)As;
    int tid = threadIdx.x;
    int wt = tid >> 6;
    int lane = tid & 63;
    int row0 = blockIdx.x * 128;
    int rload = row0 + wt * 32 + (lane & 31);
    if (rload > NN - 1) rload = NN - 1;  // clamp OOB loads
    int koff = (lane >> 5) * 8;
    const s8v* Bv = (const s8v*)Bpk;

    f16v acc[4];
#pragma unroll
    for (int n = 0; n < 4; n++) acc[n] = (f16v)(0.0f);

#pragma unroll
    for (int c = 0; c < 16; c++) {
        const u16* s = srcA;
        int kk = c * 16;
        if (c >= 8) { s = srcB; kk = (c - 8) * 16; }
        s8v a = *(const s8v*)(s + (size_t)rload * DD + kk + koff);
#pragma unroll
        for (int n = 0; n < 4; n++) {
            s8v b = Bv[(c * 4 + n) * 64 + lane];
            acc[n] = __builtin_amdgcn_mfma_f32_32x32x16_bf16(a, b, acc[n], 0, 0, 0);
        }
    }

    // relu'd bf16 acc -> LDS (C/D layout col=lane&31, row=(reg&3)+8*(reg>>2)+4*(lane>>5))
    int rowadd = 4 * (lane >> 5);
#pragma unroll
    for (int n = 0; n < 4; n++) {
        int colj = n * 32 + (lane & 31);
        float bj = bias[colj];
#pragma unroll
        for (int r = 0; r < 16; r++) {
            int rloc = wt * 32 + (r & 3) + 8 * (r >> 2) + rowadd;
            float v = fmaxf(acc[n][r] + bj, 0.0f);
            *(u16*)(Ab + rloc * 256 + ((colj * 2) ^ ((rloc & 7) << 4))) = f2bf(v);
        }
    }
    __syncthreads();

    // coalesced dual-layout store from LDS (8B per thread per iter)
#pragma unroll
    for (int it = 0; it < 16; it++) {
        int flat = it * 256 + tid;   // 0..4095
        int rl = flat >> 5;          // 0..127
        int p  = flat & 31;          // ushort4 within row
        u64t v = *(const u64t*)(Ab + rl * 256 + ((p * 8) ^ ((rl & 7) << 4)));
        int row = row0 + rl;
        if (row < NN) {
            *(u64t*)(outh + (size_t)row * DD + p * 4) = v;
            *(u64t*)(outT + (((size_t)((p >> 3) * NN + row)) << 5) + (p & 7) * 4) = v;
        }
    }
}

// ---- layer-1 GEMM + final linear fused: relu bf16 tile -> LDS -> 2nd MFMA ----
__global__ __launch_bounds__(256) void gemm_final(const u16* __restrict__ srcA,
                                                  const u16* __restrict__ srcB,
                                                  const u16* __restrict__ Bpk,
                                                  const float* __restrict__ bias,
                                                  const u16* __restrict__ Bpkf,
                                                  const float* __restrict__ bfin,
                                                  float* __restrict__ out) {
    __shared__ u16 As[128 * 128];  // 32 KB, XOR-swizzled rows
    char* Ab = (char*)As;
    int tid = threadIdx.x;
    int wt = tid >> 6;
    int lane = tid & 63;
    int row0 = blockIdx.x * 128;
    int arl = wt * 32 + (lane & 31);
    int rg = row0 + arl;
    if (rg > NN - 1) rg = NN - 1;
    int koff = (lane >> 5) * 8;
    int swz = (arl & 7) << 4;
    const s8v* Bv = (const s8v*)Bpk;

    f16v acc[4];
#pragma unroll
    for (int n = 0; n < 4; n++) acc[n] = (f16v)(0.0f);

#pragma unroll
    for (int c = 0; c < 16; c++) {
        const u16* s = srcA;
        int kk = c * 16;
        if (c >= 8) { s = srcB; kk = (c - 8) * 16; }
        s8v a = *(const s8v*)(s + (size_t)rg * DD + kk + koff);
#pragma unroll
        for (int n = 0; n < 4; n++) {
            s8v b = Bv[(c * 4 + n) * 64 + lane];
            acc[n] = __builtin_amdgcn_mfma_f32_32x32x16_bf16(a, b, acc[n], 0, 0, 0);
        }
    }

    // relu'd bf16 acc -> LDS (this tile IS the A-operand of the final linear)
    int rowadd = 4 * (lane >> 5);
#pragma unroll
    for (int n = 0; n < 4; n++) {
        int colj = n * 32 + (lane & 31);
        float bj = bias[colj];
#pragma unroll
        for (int r = 0; r < 16; r++) {
            int rloc = wt * 32 + (r & 3) + 8 * (r >> 2) + rowadd;
            float v = fmaxf(acc[n][r] + bj, 0.0f);
            *(u16*)(Ab + rloc * 256 + ((colj * 2) ^ ((rloc & 7) << 4))) = f2bf(v);
        }
    }
    __syncthreads();

    // final GEMM: K=128 from LDS, B = Bpkf
    const s8v* Bvf = (const s8v*)Bpkf;
    f16v acc2[4];
#pragma unroll
    for (int n = 0; n < 4; n++) acc2[n] = (f16v)(0.0f);
#pragma unroll
    for (int c = 0; c < 8; c++) {
        s8v a = *(const s8v*)(Ab + arl * 256 + (((c * 16 + koff) * 2) ^ swz));
#pragma unroll
        for (int n = 0; n < 4; n++) {
            s8v b = Bvf[(c * 4 + n) * 64 + lane];
            acc2[n] = __builtin_amdgcn_mfma_f32_32x32x16_bf16(a, b, acc2[n], 0, 0, 0);
        }
    }
#pragma unroll
    for (int n = 0; n < 4; n++) {
        int colj = n * 32 + (lane & 31);
        float bj = bfin[colj];
#pragma unroll
        for (int r = 0; r < 16; r++) {
            int row = row0 + wt * 32 + (r & 3) + 8 * (r >> 2) + rowadd;
            if (row < NN)
                out[(size_t)row * DD + colj] = acc2[n][r] + bj;
        }
    }
}

extern "C" void kernel_launch(void* const* d_in, const int* in_sizes, int n_in,
                              void* d_out, int out_size, void* d_ws, size_t ws_size,
                              hipStream_t stream) {
    const float* x  = (const float*)d_in[0];
    const int*   ei = (const int*)d_in[1];
    const float* Wl = (const float*)d_in[2];
    const float* bl = (const float*)d_in[3];
    const float* Wr = (const float*)d_in[4];
    const float* W  = (const float*)d_in[5];
    const float* b  = (const float*)d_in[6];
    float* out = (float*)d_out;

    // ws layout (16B-aligned chunks)
    u16* aggb = (u16*)d_ws;                         // NN*DD bf16
    u16* hb0  = aggb + (size_t)NN * DD;             // NN*DD
    u16* hb1  = hb0 + (size_t)NN * DD;              // NN*DD
    u16* hbT  = hb1 + (size_t)NN * DD;              // NN*DD (chunk-major, reused L0/L1)
    u16* Bpk0 = hbT + (size_t)NN * DD;              // 32768
    u16* Bpk1 = Bpk0 + 32768;                       // 32768
    u16* Bpkf = Bpk1 + 32768;                       // 16384
    unsigned* packed = (unsigned*)(Bpkf + 16384);   // NE u32
    int* col    = (int*)(packed + NE);              // NE
    int* rowptr = col + NE;                         // NN+1
    int* bcnt   = rowptr + NN + 1;                  // NBUCK
    int* claim  = bcnt + NBUCK;                     // NBUCK
    int* qctr   = claim + NBUCK;                    // 2 (per-layer agg queue tickets)

    dim3 blk(256);
    int gemmBlocks = (NN + 127) / 128;   // 391
    int aggBlocks  = 2048;               // persistent-ish workers, queue-fed
    int prepBlocks = CONVB + 320 + PB;   // conv + 3 packs + hist

    // zero bcnt+claim+qctr, then fused prep (conv+transpose | packs | hist)
    zero_kernel<<<2, blk, 0, stream>>>(bcnt, 2 * NBUCK + 2);
    prep_kernel<<<prepBlocks, blk, 0, stream>>>(
        (const float4*)x, (ushort4*)hb0, (ushort4*)hbT, Wl, Wr, W,
        Bpk0, Bpk1, Bpkf, ei, bcnt);

    // CSR build
    bucket_partition<<<PB, blk, 0, stream>>>(ei, bcnt, claim, packed, rowptr);
    bucket_csr<<<NBUCK, blk, 0, stream>>>(packed, bcnt, rowptr, col);

    // Layer 0: chunk-serialized agg (hbT = x chunk-major) -> GEMM (writes hb1 + hbT)
    agg_chunked_q<<<aggBlocks, blk, 0, stream>>>(
        (const uint4*)hbT, rowptr, col, (uint4*)aggb, qctr);
    mfma_gemm0<<<gemmBlocks, blk, 0, stream>>>(aggb, hb0, Bpk0, bl, hb1, hbT);

    // Layer 1 + final linear fused
    agg_chunked_q<<<aggBlocks, blk, 0, stream>>>(
        (const uint4*)hbT, rowptr, col, (uint4*)aggb, qctr + 1);
    gemm_final<<<gemmBlocks, blk, 0, stream>>>(aggb, hb1, Bpk1, bl + DD, Bpkf, b, out);
}

// Round 6
// 237.933 us; speedup vs baseline: 1.3745x; 1.3745x over previous
//
#include <hip/hip_runtime.h>
#include <math.h>

#define NN 50000
#define NE 800000
#define DD 128
#define NBUCK 196        // ceil(NN/256) buckets of 256 nodes
#define EPB 2048         // edges per hist/partition block
#define PB 391           // ceil(NE/EPB)
#define CONVB 6250       // NN*DD/4/256

typedef unsigned short u16;
typedef unsigned long long u64t;
typedef short s8v __attribute__((ext_vector_type(8)));    // 8 bf16 (4 VGPRs)
typedef float f16v __attribute__((ext_vector_type(16)));  // 16 fp32 acc

__device__ __forceinline__ u16 f2bf(float f) {  // RNE fp32->bf16
    unsigned u = __float_as_uint(f);
    return (u16)((u + 0x7FFFu + ((u >> 16) & 1u)) >> 16);
}
__device__ __forceinline__ float bflo(unsigned u) { return __uint_as_float(u << 16); }
__device__ __forceinline__ float bfhi(unsigned u) { return __uint_as_float(u & 0xFFFF0000u); }

// ---- zero bcnt + claim (graph-capture-safe) ----
__global__ __launch_bounds__(256) void zero_kernel(int* __restrict__ p, int n) {
    int i = threadIdx.x + blockIdx.x * 256;
    if (i < n) p[i] = 0;
}

// ---- fused prep: x->bf16 conv | 3x weight pack | edge histogram ----
// pack order: out[((c*4+n)*64+l)*8+j] = Wcat[col=n*32+(l&31)][k=c*16+(l>>5)*8+j]
__device__ __forceinline__ void pack_one(const float* __restrict__ Wl,
                                         const float* __restrict__ Wr,
                                         bool two, int o, u16* __restrict__ out) {
    int j = o & 7;
    int l = (o >> 3) & 63;
    int cn = o >> 9;
    int n = cn & 3;
    int c = cn >> 2;
    int colj = n * 32 + (l & 31);
    int k = c * 16 + (l >> 5) * 8 + j;
    float v;
    if (two) v = (k < DD) ? Wl[colj * DD + k] : Wr[colj * DD + (k - DD)];
    else     v = Wl[colj * DD + k];
    out[o] = f2bf(v);
}

__global__ __launch_bounds__(256) void prep_kernel(
        const float4* __restrict__ x4, ushort4* __restrict__ hb0,
        const float* __restrict__ Wl, const float* __restrict__ Wr,
        const float* __restrict__ W,
        u16* __restrict__ Bpk0, u16* __restrict__ Bpk1, u16* __restrict__ Bpkf,
        const int* __restrict__ ei, int* __restrict__ bcnt) {
    int bid = blockIdx.x;
    int tid = threadIdx.x;
    if (bid < CONVB) {
        int i = bid * 256 + tid;
        float4 v = x4[i];
        ushort4 o;
        o.x = f2bf(v.x); o.y = f2bf(v.y); o.z = f2bf(v.z); o.w = f2bf(v.w);
        hb0[i] = o;
    } else if (bid < CONVB + 128) {
        pack_one(Wl, Wr, true, (bid - CONVB) * 256 + tid, Bpk0);
    } else if (bid < CONVB + 256) {
        pack_one(Wl + DD * DD, Wr + DD * DD, true, (bid - CONVB - 128) * 256 + tid, Bpk1);
    } else if (bid < CONVB + 320) {
        pack_one(W, W, false, (bid - CONVB - 256) * 256 + tid, Bpkf);
    } else {
        // coarse bucket histogram (bcnt zeroed by zero_kernel)
        __shared__ int h[NBUCK];
        for (int i = tid; i < NBUCK; i += 256) h[i] = 0;
        __syncthreads();
        int e0 = (bid - (CONVB + 320)) * EPB;
#pragma unroll
        for (int i = 0; i < 8; i++) {
            int e = e0 + i * 256 + tid;
            if (e < NE) atomicAdd(&h[ei[NE + e] >> 8], 1);
        }
        __syncthreads();
        for (int i = tid; i < NBUCK; i += 256)
            if (h[i]) atomicAdd(&bcnt[i], h[i]);
    }
}

// ---- partition edges into bucket-contiguous packed array ----
__global__ __launch_bounds__(256) void bucket_partition(const int* __restrict__ ei,
                                                        const int* __restrict__ bcnt,
                                                        int* __restrict__ claim,
                                                        unsigned* __restrict__ packed,
                                                        int* __restrict__ rowptr) {
    __shared__ int sc[256];
    __shared__ int bb[NBUCK];
    __shared__ int h[NBUCK];
    __shared__ int base[NBUCK];
    int t = threadIdx.x;
    int v = (t < NBUCK) ? bcnt[t] : 0;
    sc[t] = v;
    __syncthreads();
    for (int o = 1; o < 256; o <<= 1) {
        int u = (t >= o) ? sc[t - o] : 0;
        __syncthreads();
        sc[t] += u;
        __syncthreads();
    }
    if (t < NBUCK) bb[t] = sc[t] - v;
    if (t == 0 && blockIdx.x == 0) rowptr[NN] = NE;
    for (int i = t; i < NBUCK; i += 256) h[i] = 0;
    __syncthreads();
    int e0 = blockIdx.x * EPB;
    int dsts[8], srcs[8];
#pragma unroll
    for (int i = 0; i < 8; i++) {
        int e = e0 + i * 256 + t;
        if (e < NE) {
            dsts[i] = ei[NE + e];
            srcs[i] = ei[e];
            atomicAdd(&h[dsts[i] >> 8], 1);
        } else dsts[i] = -1;
    }
    __syncthreads();
    for (int i = t; i < NBUCK; i += 256) {
        int c = h[i];
        base[i] = c ? bb[i] + atomicAdd(&claim[i], c) : 0;
    }
    __syncthreads();
    for (int i = t; i < NBUCK; i += 256) h[i] = 0;  // reuse as local cursor
    __syncthreads();
#pragma unroll
    for (int i = 0; i < 8; i++) {
        if (dsts[i] >= 0) {
            int bk = dsts[i] >> 8;
            int r = atomicAdd(&h[bk], 1);
            packed[base[bk] + r] = (unsigned)srcs[i] | ((unsigned)(dsts[i] & 255) << 16);
        }
    }
}

// ---- per-bucket counting sort -> rowptr + col ----
__global__ __launch_bounds__(256) void bucket_csr(const unsigned* __restrict__ packed,
                                                  const int* __restrict__ bcnt,
                                                  int* __restrict__ rowptr,
                                                  int* __restrict__ col) {
    __shared__ int sc[256];
    __shared__ int deg[256];
    __shared__ int off[256];
    int t = threadIdx.x;
    int v0 = (t < NBUCK) ? bcnt[t] : 0;
    sc[t] = v0;
    __syncthreads();
    for (int o = 1; o < 256; o <<= 1) {
        int u = (t >= o) ? sc[t - o] : 0;
        __syncthreads();
        sc[t] += u;
        __syncthreads();
    }
    int bk = blockIdx.x;
    int cnt = bcnt[bk];
    int base = sc[bk] - cnt;  // exclusive scan value for this bucket
    deg[t] = 0;
    __syncthreads();
    for (int i = t; i < cnt; i += 256) atomicAdd(&deg[packed[base + i] >> 16], 1);
    __syncthreads();
    int v = deg[t];
    off[t] = v;
    __syncthreads();
    for (int o = 1; o < 256; o <<= 1) {
        int u = (t >= o) ? off[t - o] : 0;
        __syncthreads();
        off[t] += u;
        __syncthreads();
    }
    int ex = off[t] - v;
    int node = (bk << 8) + t;
    if (node < NN) rowptr[node] = base + ex;
    deg[t] = ex;  // reuse as cursor
    __syncthreads();
    for (int i = t; i < cnt; i += 256) {
        unsigned p = packed[base + i];
        int dl = p >> 16;
        int r = atomicAdd(&deg[dl], 1);
        col[base + r] = (int)(p & 0xFFFFu);
    }
}

// ---- segmented max on bf16 (CSR), 16 lanes/node, 16B/lane ----
// Batch-16 issue-then-consume: 16 gathers in flight per lane before first fmax,
// so the LLC latency is exposed ~once per 16 edges (deg avg = 16 -> ~1 exposure).
__device__ __forceinline__ void vmax8(float* m, uint4 v) {
    m[0] = fmaxf(m[0], bflo(v.x)); m[1] = fmaxf(m[1], bfhi(v.x));
    m[2] = fmaxf(m[2], bflo(v.y)); m[3] = fmaxf(m[3], bfhi(v.y));
    m[4] = fmaxf(m[4], bflo(v.z)); m[5] = fmaxf(m[5], bfhi(v.z));
    m[6] = fmaxf(m[6], bflo(v.w)); m[7] = fmaxf(m[7], bfhi(v.w));
}

__global__ __launch_bounds__(256) void agg_kernel_bf(const uint4* __restrict__ xb4,
                                                     const int* __restrict__ row_ptr,
                                                     const int* __restrict__ col,
                                                     uint4* __restrict__ aggb4) {
    int node = blockIdx.x * 16 + (threadIdx.x >> 4);
    if (node >= NN) return;
    int j = threadIdx.x & 15;
    int s0 = row_ptr[node], s1 = row_ptr[node + 1];
    if (s0 == s1) {
        aggb4[(size_t)node * 16 + j] = make_uint4(0, 0, 0, 0);
        return;
    }
    float m0[8], m1[8], m2[8], m3[8];
#pragma unroll
    for (int q = 0; q < 8; q++) { m0[q] = m1[q] = m2[q] = m3[q] = -INFINITY; }
    int i = s0;
    // main: 16 edges per batch, all loads issued before any consumption
    for (; i + 16 <= s1; i += 16) {
        uint4 vv[16];
#pragma unroll
        for (int k = 0; k < 16; k++) vv[k] = xb4[(size_t)col[i + k] * 16 + j];
#pragma unroll
        for (int k = 0; k < 16; k++) {
            if ((k & 3) == 0) vmax8(m0, vv[k]);
            else if ((k & 3) == 1) vmax8(m1, vv[k]);
            else if ((k & 3) == 2) vmax8(m2, vv[k]);
            else vmax8(m3, vv[k]);
        }
    }
    for (; i + 8 <= s1; i += 8) {
        uint4 vv[8];
#pragma unroll
        for (int k = 0; k < 8; k++) vv[k] = xb4[(size_t)col[i + k] * 16 + j];
#pragma unroll
        for (int k = 0; k < 8; k++) {
            if ((k & 3) == 0) vmax8(m0, vv[k]);
            else if ((k & 3) == 1) vmax8(m1, vv[k]);
            else if ((k & 3) == 2) vmax8(m2, vv[k]);
            else vmax8(m3, vv[k]);
        }
    }
    for (; i + 4 <= s1; i += 4) {
        uint4 v0 = xb4[(size_t)col[i] * 16 + j];
        uint4 v1 = xb4[(size_t)col[i + 1] * 16 + j];
        uint4 v2 = xb4[(size_t)col[i + 2] * 16 + j];
        uint4 v3 = xb4[(size_t)col[i + 3] * 16 + j];
        vmax8(m0, v0); vmax8(m1, v1); vmax8(m2, v2); vmax8(m3, v3);
    }
    for (; i < s1; i++) {
        uint4 v = xb4[(size_t)col[i] * 16 + j];
        vmax8(m0, v);
    }
#pragma unroll
    for (int q = 0; q < 8; q++) m0[q] = fmaxf(fmaxf(m0[q], m1[q]), fmaxf(m2[q], m3[q]));
    uint4 o;  // values are exact bf16 -> pack by truncation
    o.x = (__float_as_uint(m0[0]) >> 16) | (__float_as_uint(m0[1]) & 0xFFFF0000u);
    o.y = (__float_as_uint(m0[2]) >> 16) | (__float_as_uint(m0[3]) & 0xFFFF0000u);
    o.z = (__float_as_uint(m0[4]) >> 16) | (__float_as_uint(m0[5]) & 0xFFFF0000u);
    o.w = (__float_as_uint(m0[6]) >> 16) | (__float_as_uint(m0[7]) & 0xFFFF0000u);
    aggb4[(size_t)node * 16 + j] = o;
}

// ---------------- MFMA GEMM layer 0: LDS-staged coalesced epilogue ----------------
// out[row][col] = relu(bias[col] + sum_k A[row][k]*Wcat[col][k]); A=[aggb|hb0], K=256.
__global__ __launch_bounds__(256) void mfma_gemm0(const u16* __restrict__ srcA,
                                                  const u16* __restrict__ srcB,
                                                  const u16* __restrict__ Bpk,
                                                  const float* __restrict__ bias,
                                                  u16* __restrict__ outh) {
    __shared__ u16 As[128 * 128];  // 32 KB, XOR-swizzled rows
    char* Ab = (char*)As;
    int tid = threadIdx.x;
    int wt = tid >> 6;
    int lane = tid & 63;
    int row0 = blockIdx.x * 128;
    int rload = row0 + wt * 32 + (lane & 31);
    if (rload > NN - 1) rload = NN - 1;  // clamp OOB loads
    int koff = (lane >> 5) * 8;
    const s8v* Bv = (const s8v*)Bpk;

    f16v acc[4];
#pragma unroll
    for (int n = 0; n < 4; n++) acc[n] = (f16v)(0.0f);

#pragma unroll
    for (int c = 0; c < 16; c++) {
        const u16* s = srcA;
        int kk = c * 16;
        if (c >= 8) { s = srcB; kk = (c - 8) * 16; }
        s8v a = *(const s8v*)(s + (size_t)rload * DD + kk + koff);
#pragma unroll
        for (int n = 0; n < 4; n++) {
            s8v b = Bv[(c * 4 + n) * 64 + lane];
            acc[n] = __builtin_amdgcn_mfma_f32_32x32x16_bf16(a, b, acc[n], 0, 0, 0);
        }
    }

    // relu'd bf16 acc -> LDS (C/D layout col=lane&31, row=(reg&3)+8*(reg>>2)+4*(lane>>5))
    int rowadd = 4 * (lane >> 5);
#pragma unroll
    for (int n = 0; n < 4; n++) {
        int colj = n * 32 + (lane & 31);
        float bj = bias[colj];
#pragma unroll
        for (int r = 0; r < 16; r++) {
            int rloc = wt * 32 + (r & 3) + 8 * (r >> 2) + rowadd;
            float v = fmaxf(acc[n][r] + bj, 0.0f);
            *(u16*)(Ab + rloc * 256 + ((colj * 2) ^ ((rloc & 7) << 4))) = f2bf(v);
        }
    }
    __syncthreads();

    // coalesced store from LDS (8B per thread per iter)
#pragma unroll
    for (int it = 0; it < 16; it++) {
        int flat = it * 256 + tid;   // 0..4095
        int rl = flat >> 5;          // 0..127
        int p  = flat & 31;          // ushort4 within row
        u64t v = *(const u64t*)(Ab + rl * 256 + ((p * 8) ^ ((rl & 7) << 4)));
        int row = row0 + rl;
        if (row < NN)
            *(u64t*)(outh + (size_t)row * DD + p * 4) = v;
    }
}

// ---- layer-1 GEMM + final linear fused: relu bf16 tile -> LDS -> 2nd MFMA ----
__global__ __launch_bounds__(256) void gemm_final(const u16* __restrict__ srcA,
                                                  const u16* __restrict__ srcB,
                                                  const u16* __restrict__ Bpk,
                                                  const float* __restrict__ bias,
                                                  const u16* __restrict__ Bpkf,
                                                  const float* __restrict__ bfin,
                                                  float* __restrict__ out) {
    __shared__ u16 As[128 * 128];  // 32 KB, XOR-swizzled rows
    char* Ab = (char*)As;
    int tid = threadIdx.x;
    int wt = tid >> 6;
    int lane = tid & 63;
    int row0 = blockIdx.x * 128;
    int arl = wt * 32 + (lane & 31);
    int rg = row0 + arl;
    if (rg > NN - 1) rg = NN - 1;
    int koff = (lane >> 5) * 8;
    int swz = (arl & 7) << 4;
    const s8v* Bv = (const s8v*)Bpk;

    f16v acc[4];
#pragma unroll
    for (int n = 0; n < 4; n++) acc[n] = (f16v)(0.0f);

#pragma unroll
    for (int c = 0; c < 16; c++) {
        const u16* s = srcA;
        int kk = c * 16;
        if (c >= 8) { s = srcB; kk = (c - 8) * 16; }
        s8v a = *(const s8v*)(s + (size_t)rg * DD + kk + koff);
#pragma unroll
        for (int n = 0; n < 4; n++) {
            s8v b = Bv[(c * 4 + n) * 64 + lane];
            acc[n] = __builtin_amdgcn_mfma_f32_32x32x16_bf16(a, b, acc[n], 0, 0, 0);
        }
    }

    // relu'd bf16 acc -> LDS (this tile IS the A-operand of the final linear)
    int rowadd = 4 * (lane >> 5);
#pragma unroll
    for (int n = 0; n < 4; n++) {
        int colj = n * 32 + (lane & 31);
        float bj = bias[colj];
#pragma unroll
        for (int r = 0; r < 16; r++) {
            int rloc = wt * 32 + (r & 3) + 8 * (r >> 2) + rowadd;
            float v = fmaxf(acc[n][r] + bj, 0.0f);
            *(u16*)(Ab + rloc * 256 + ((colj * 2) ^ ((rloc & 7) << 4))) = f2bf(v);
        }
    }
    __syncthreads();

    // final GEMM: K=128 from LDS, B = Bpkf
    const s8v* Bvf = (const s8v*)Bpkf;
    f16v acc2[4];
#pragma unroll
    for (int n = 0; n < 4; n++) acc2[n] = (f16v)(0.0f);
#pragma unroll
    for (int c = 0; c < 8; c++) {
        s8v a = *(const s8v*)(Ab + arl * 256 + (((c * 16 + koff) * 2) ^ swz));
#pragma unroll
        for (int n = 0; n < 4; n++) {
            s8v b = Bvf[(c * 4 + n) * 64 + lane];
            acc2[n] = __builtin_amdgcn_mfma_f32_32x32x16_bf16(a, b, acc2[n], 0, 0, 0);
        }
    }
#pragma unroll
    for (int n = 0; n < 4; n++) {
        int colj = n * 32 + (lane & 31);
        float bj = bfin[colj];
#pragma unroll
        for (int r = 0; r < 16; r++) {
            int row = row0 + wt * 32 + (r & 3) + 8 * (r >> 2) + rowadd;
            if (row < NN)
                out[(size_t)row * DD + colj] = acc2[n][r] + bj;
        }
    }
}

extern "C" void kernel_launch(void* const* d_in, const int* in_sizes, int n_in,
                              void* d_out, int out_size, void* d_ws, size_t ws_size,
                              hipStream_t stream) {
    const float* x  = (const float*)d_in[0];
    const int*   ei = (const int*)d_in[1];
    const float* Wl = (const float*)d_in[2];
    const float* bl = (const float*)d_in[3];
    const float* Wr = (const float*)d_in[4];
    const float* W  = (const float*)d_in[5];
    const float* b  = (const float*)d_in[6];
    float* out = (float*)d_out;

    // ws layout (16B-aligned chunks)
    u16* aggb = (u16*)d_ws;                         // NN*DD bf16
    u16* hb0  = aggb + (size_t)NN * DD;             // NN*DD
    u16* hb1  = hb0 + (size_t)NN * DD;              // NN*DD
    u16* Bpk0 = hb1 + (size_t)NN * DD;              // 32768
    u16* Bpk1 = Bpk0 + 32768;                       // 32768
    u16* Bpkf = Bpk1 + 32768;                       // 16384
    unsigned* packed = (unsigned*)(Bpkf + 16384);   // NE u32
    int* col    = (int*)(packed + NE);              // NE
    int* rowptr = col + NE;                         // NN+1
    int* bcnt   = rowptr + NN + 1;                  // NBUCK
    int* claim  = bcnt + NBUCK;                     // NBUCK

    dim3 blk(256);
    int gemmBlocks = (NN + 127) / 128;   // 391
    int aggBlocks  = (NN + 15) / 16;     // 3125
    int prepBlocks = CONVB + 320 + PB;   // conv + 3 packs + hist

    // zero bcnt+claim, then fused prep (conv | packs | hist)
    zero_kernel<<<2, blk, 0, stream>>>(bcnt, 2 * NBUCK);
    prep_kernel<<<prepBlocks, blk, 0, stream>>>(
        (const float4*)x, (ushort4*)hb0, Wl, Wr, W, Bpk0, Bpk1, Bpkf, ei, bcnt);

    // CSR build
    bucket_partition<<<PB, blk, 0, stream>>>(ei, bcnt, claim, packed, rowptr);
    bucket_csr<<<NBUCK, blk, 0, stream>>>(packed, bcnt, rowptr, col);

    // Layer 0
    agg_kernel_bf<<<aggBlocks, blk, 0, stream>>>((const uint4*)hb0, rowptr, col, (uint4*)aggb);
    mfma_gemm0<<<gemmBlocks, blk, 0, stream>>>(aggb, hb0, Bpk0, bl, hb1);

    // Layer 1 + final linear fused
    agg_kernel_bf<<<aggBlocks, blk, 0, stream>>>((const uint4*)hb1, rowptr, col, (uint4*)aggb);
    gemm_final<<<gemmBlocks, blk, 0, stream>>>(aggb, hb1, Bpk1, bl + DD, Bpkf, b, out);
}